// Round 7
// baseline (443.848 us; speedup 1.0000x reference)
//
#include <hip/hip_runtime.h>

#define EMBED_D  2048
#define N_EXP    64
#define K_TOP    8
#define TOK_BLK  32
#define THREADS  256            // 4 waves: (tg 0/1 = 16-token group) x (eh 0/1 = 32-expert half)
#define NCHUNK   64             // K chunks of 32
#define WCHUNK_B 12288          // W frag bytes per K32 chunk: 3 planes * 4 n * 64 lanes * 16
#define NBUF     3

typedef __attribute__((ext_vector_type(8))) short bf16x8;   // 8 bf16 = 4 VGPR
typedef __attribute__((ext_vector_type(4))) float f32x4;    // MFMA C/D

__device__ __forceinline__ uint bf16_rne(float x) {
    uint u = __float_as_uint(x);
    return (u + 0x7fffu + ((u >> 16) & 1u)) >> 16;
}
__device__ __forceinline__ float bf16f(uint h) { return __uint_as_float(h << 16); }

// direct global->LDS, 16 B per lane; LDS dest = wave-uniform base + lane*16
__device__ __forceinline__ void stage16(const void* g, void* l)
{
    typedef __attribute__((address_space(1))) const unsigned int gu32;
    typedef __attribute__((address_space(3))) unsigned int lu32;
    __builtin_amdgcn_global_load_lds((gu32*)g, (lu32*)l, 16, 0, 0);
}

// x[8] -> h/m/l bf16x8. h,m: RNE; l: trunc. Identical to R4-R6 -> same logits.
__device__ __forceinline__ void split3(float4 u, float4 v, bf16x8& H, bf16x8& M, bf16x8& L)
{
    const float x[8] = {u.x, u.y, u.z, u.w, v.x, v.y, v.z, v.w};
    uint hw[8], mw[8], lw[8];
#pragma unroll
    for (int j = 0; j < 8; ++j) {
        const uint ux = __float_as_uint(x[j]);
        hw[j] = (ux + 0x7fffu + ((ux >> 16) & 1u)) & 0xffff0000u;   // RNE, low16 zero
        const float r1 = x[j] - __uint_as_float(hw[j]);             // exact
        const uint ur = __float_as_uint(r1);
        mw[j] = (ur + 0x7fffu + ((ur >> 16) & 1u)) & 0xffff0000u;   // RNE
        lw[j] = __float_as_uint(r1 - __uint_as_float(mw[j]));       // trunc via pack
    }
    uint* hp = (uint*)&H; uint* mp = (uint*)&M; uint* lp = (uint*)&L;
#pragma unroll
    for (int w = 0; w < 4; ++w) {
        hp[w] = __builtin_amdgcn_perm(hw[2 * w + 1], hw[2 * w], 0x07060302u);
        mp[w] = __builtin_amdgcn_perm(mw[2 * w + 1], mw[2 * w], 0x07060302u);
        lp[w] = __builtin_amdgcn_perm(lw[2 * w + 1], lw[2 * w], 0x07060302u);
    }
}

// W[64][2048] fp32 -> fragment-major h/m/l planes, K32-block layout (same as R5/R6).
// Byte offs: c32*12288 + p*4096 + n*1024 + lane*16; e = n*16+row, k = c32*32+g*8+j,
// lane = g*16+row.
__global__ void w_prep(const float* __restrict__ W, ushort* __restrict__ WF)
{
    const int e = blockIdx.x;
    const int t = threadIdx.x;
    const float4 a = *(const float4*)(W + (size_t)e * EMBED_D + t * 8);
    const float4 b = *(const float4*)(W + (size_t)e * EMBED_D + t * 8 + 4);
    const float ev[8] = {a.x, a.y, a.z, a.w, b.x, b.y, b.z, b.w};
    ushort h[8], m[8], l[8];
#pragma unroll
    for (int j = 0; j < 8; ++j) {
        const uint hh = bf16_rne(ev[j]);
        const float r1 = ev[j] - bf16f(hh);
        const uint mm = bf16_rne(r1);
        const uint ll = bf16_rne(r1 - bf16f(mm));
        h[j] = (ushort)hh; m[j] = (ushort)mm; l[j] = (ushort)ll;
    }
    const int c = t >> 2;           // K32 block
    const int g = t & 3;
    const int lane = g * 16 + (e & 15);
    const int n    = e >> 4;
    const size_t base = (size_t)c * 6144 + (size_t)n * 512 + (size_t)lane * 8;  // ushorts
    ushort4* H = (ushort4*)(WF + base);
    ushort4* M = (ushort4*)(WF + base + 2048);
    ushort4* L = (ushort4*)(WF + base + 4096);
    H[0] = make_ushort4(h[0], h[1], h[2], h[3]); H[1] = make_ushort4(h[4], h[5], h[6], h[7]);
    M[0] = make_ushort4(m[0], m[1], m[2], m[3]); M[1] = make_ushort4(m[4], m[5], m[6], m[7]);
    L[0] = make_ushort4(l[0], l[1], l[2], l[3]); L[1] = make_ushort4(l[4], l[5], l[6], l[7]);
}

__global__ __launch_bounds__(THREADS, 4) void moe_gate_main(
    const float*  __restrict__ X,    // [n_tok][2048] fp32
    const ushort* __restrict__ WF,   // fragment-major W planes (768 KB)
    float* __restrict__ out,
    float* __restrict__ ws,
    int n_tok)
{
    // 3 W pipeline slots (36 KB) -> 4 blocks/CU; reused as Lp[32][65] after loop.
    __shared__ __align__(16) char smem[NBUF * WCHUNK_B];
    __shared__ float sInvZ[TOK_BLK];
    __shared__ float sCnt[N_EXP];
    __shared__ float sColp[4][N_EXP];

    const int tid  = threadIdx.x;
    const int lane = tid & 63;
    const int wv   = __builtin_amdgcn_readfirstlane(tid >> 6);  // 0..3
    const int tg   = wv >> 1;     // 16-token group
    const int eh   = wv & 1;      // 32-expert half
    const int row  = lane & 15;
    const int g    = lane >> 4;
    const int t0   = blockIdx.x * TOK_BLK;

    // X straight to registers: lane holds token (tg*16+row), k-group g (8 floats/chunk)
    const float* xbase = X + (size_t)(t0 + tg * 16 + row) * EMBED_D + (g << 3);
    // W staging source: this wave's 3 x 1KB pieces per chunk (linear copy)
    const char* wsrc = (const char*)WF + (size_t)(wv * 1024) + lane * 16;

    f32x4 acc[2];
    acc[0] = (f32x4){0.f, 0.f, 0.f, 0.f};
    acc[1] = (f32x4){0.f, 0.f, 0.f, 0.f};

    float4 xc0, xc1, xn0, xn1;

    // ---- prologue: batch0 (X c0 + W c0 -> slot0), batch1 (X c1 + W c1 -> slot1) ----
    xc0 = *(const float4*)(xbase);
    xc1 = *(const float4*)(xbase + 4);
#pragma unroll
    for (int r = 0; r < 3; ++r)
        stage16(wsrc + r * 4096, smem + (r * 4 + wv) * 1024);
    __builtin_amdgcn_sched_barrier(0);
    xn0 = *(const float4*)(xbase + 32);
    xn1 = *(const float4*)(xbase + 36);
#pragma unroll
    for (int r = 0; r < 3; ++r)
        stage16(wsrc + WCHUNK_B + r * 4096, smem + WCHUNK_B + (r * 4 + wv) * 1024);
    __builtin_amdgcn_sched_barrier(0);

    int s_cur = 0;
    for (int c = 0; c < NCHUNK; ++c) {
        // (1) counted wait: batch c landed; batch c+1 (5 ops) may stay in flight
        if (c + 1 < NCHUNK) asm volatile("s_waitcnt vmcnt(5)" ::: "memory");
        else                asm volatile("s_waitcnt vmcnt(0)" ::: "memory");
        __builtin_amdgcn_sched_barrier(0);
        __builtin_amdgcn_s_barrier();    // slot(c) ready for all; slot(c-1) free
        __builtin_amdgcn_sched_barrier(0);

        // (2) issue batch c+2: 2 X loads (to temps) + 3 W stages into slot (c+2)%3
        float4 tq0 = {0, 0, 0, 0}, tq1 = {0, 0, 0, 0};
        if (c + 2 < NCHUNK) {
            const float* xs = xbase + (c + 2) * 32;
            tq0 = *(const float4*)(xs);
            tq1 = *(const float4*)(xs + 4);
            const int s2 = (s_cur >= 1) ? s_cur - 1 : 2;   // (s_cur+2)%3
            char* db = smem + s2 * WCHUNK_B;
            const char* gw = wsrc + (size_t)(c + 2) * WCHUNK_B;
            stage16(gw,        db + (0 * 4 + wv) * 1024);
            stage16(gw + 4096, db + (1 * 4 + wv) * 1024);
            stage16(gw + 8192, db + (2 * 4 + wv) * 1024);
        }
        __builtin_amdgcn_sched_barrier(0);

        // (3) compute chunk c
        bf16x8 ah, am, al;
        split3(xc0, xc1, ah, am, al);
        const char* bb = smem + s_cur * WCHUNK_B;
#pragma unroll
        for (int nl = 0; nl < 2; ++nl) {
            const int n = eh * 2 + nl;
            const char* bp = bb + n * 1024 + (lane << 4);
            const bf16x8 bh = *(const bf16x8*)(bp);
            const bf16x8 bm = *(const bf16x8*)(bp + 4096);
            const bf16x8 bl = *(const bf16x8*)(bp + 8192);
            acc[nl] = __builtin_amdgcn_mfma_f32_16x16x32_bf16(ah, bh, acc[nl], 0, 0, 0);
            acc[nl] = __builtin_amdgcn_mfma_f32_16x16x32_bf16(am, bh, acc[nl], 0, 0, 0);
            acc[nl] = __builtin_amdgcn_mfma_f32_16x16x32_bf16(ah, bm, acc[nl], 0, 0, 0);
            acc[nl] = __builtin_amdgcn_mfma_f32_16x16x32_bf16(al, bh, acc[nl], 0, 0, 0);
            acc[nl] = __builtin_amdgcn_mfma_f32_16x16x32_bf16(ah, bl, acc[nl], 0, 0, 0);
            acc[nl] = __builtin_amdgcn_mfma_f32_16x16x32_bf16(am, bm, acc[nl], 0, 0, 0);
        }
        __builtin_amdgcn_sched_barrier(0);

        // (4) rotate
        xc0 = xn0; xc1 = xn1; xn0 = tq0; xn1 = tq1;
        s_cur = (s_cur == NBUF - 1) ? 0 : s_cur + 1;
    }
    __syncthreads();   // all waves done -> W slots reusable as Lp

    // reuse smem as logits [tok][exp], stride 65 (8320 B <= 36864 B)
    float (*Lp)[N_EXP + 1] = (float (*)[N_EXP + 1])smem;
    // C/D layout: token = tg*16 + g*4 + reg, expert = (eh*2+nl)*16 + (lane&15)
#pragma unroll
    for (int nl = 0; nl < 2; ++nl)
#pragma unroll
        for (int r = 0; r < 4; ++r)
            Lp[tg * 16 + g * 4 + r][(eh * 2 + nl) * 16 + row] = acc[nl][r];
    if (tid < N_EXP) sCnt[tid] = 0.f;
    __syncthreads();

    // per-token softmax + top-8 (threads 0..31)
    if (tid < TOK_BLK) {
        const int t = tid;
        float mx = -1e30f;
        for (int e = 0; e < N_EXP; ++e)
            mx = fmaxf(mx, Lp[t][e]);
        float Z = 0.f;
        float tv[K_TOP]; int ti[K_TOP];
#pragma unroll
        for (int j = 0; j < K_TOP; ++j) { tv[j] = -1e30f; ti[j] = 0; }
        for (int e = 0; e < N_EXP; ++e) {
            const float s = __expf(Lp[t][e] - mx);
            Lp[t][e] = s;                 // unnormalized score for Pi pass
            Z += s;
            float v = s; int id = e;
#pragma unroll
            for (int j = 0; j < K_TOP; ++j) {  // strict > : ties keep lower idx
                if (v > tv[j]) {
                    float fv = tv[j]; tv[j] = v; v = fv;
                    int   fi = ti[j]; ti[j] = id; id = fi;
                }
            }
        }
        const float invZ = 1.0f / Z;
        sInvZ[t] = invZ;
        const size_t ob = (size_t)(t0 + t) * K_TOP;
        const size_t wo = (size_t)n_tok * K_TOP;
#pragma unroll
        for (int j = 0; j < K_TOP; ++j) {
            out[ob + j]      = (float)ti[j];
            out[wo + ob + j] = tv[j] * invZ;
            atomicAdd(&sCnt[ti[j]], 1.0f);
        }
    }
    __syncthreads();

    // per-expert score sums (Pi numerator): 4 groups x 8 tokens
    {
        const int e = tid & 63, g2 = tid >> 6;
        float s = 0.f;
#pragma unroll
        for (int i = 0; i < 8; ++i) {
            const int t = g2 * 8 + i;
            s += Lp[t][e] * sInvZ[t];
        }
        sColp[g2][e] = s;
    }
    __syncthreads();
    if (tid < N_EXP) {
        float s = 0.f;
#pragma unroll
        for (int g2 = 0; g2 < 4; ++g2) s += sColp[g2][tid];
        atomicAdd(&ws[64 + tid], s);
        atomicAdd(&ws[tid], sCnt[tid]);
    }
}

__global__ void moe_aux(const float* __restrict__ ws, float* __restrict__ out, int n_tok)
{
    const int e = threadIdx.x;   // 64 threads
    const float counts = ws[e];
    const float ssum   = ws[64 + e];
    const float Pi = ssum / (float)n_tok;
    const float ce = counts / ((float)n_tok * (float)K_TOP);
    float term = Pi * ce * (float)N_EXP;
    for (int off = 32; off; off >>= 1) term += __shfl_down(term, off);
    if (e == 0) out[(size_t)2 * n_tok * K_TOP] = term * 0.01f;
}

extern "C" void kernel_launch(void* const* d_in, const int* in_sizes, int n_in,
                              void* d_out, int out_size, void* d_ws, size_t ws_size,
                              hipStream_t stream)
{
    const float* X = (const float*)d_in[0];
    const float* W = (const float*)d_in[1];
    float* out = (float*)d_out;
    float* ws  = (float*)d_ws;
    const int n_tok = in_sizes[0] / EMBED_D;   // 32768

    // workspace: [0..255] floats counters | fragment-major W planes (768 KB)
    ushort* WF = (ushort*)(ws + 256);

    hipMemsetAsync(ws, 0, 2 * N_EXP * sizeof(float), stream);
    w_prep<<<N_EXP, 256, 0, stream>>>(W, WF);
    moe_gate_main<<<n_tok / TOK_BLK, THREADS, 0, stream>>>(X, WF, out, ws, n_tok);
    moe_aux<<<1, 64, 0, stream>>>(ws, out, n_tok);
}

// Round 8
// 420.425 us; speedup vs baseline: 1.0557x; 1.0557x over previous
//
#include <hip/hip_runtime.h>

#define EMBED_D  2048
#define N_EXP    64
#define K_TOP    8
#define TOK_BLK  64
#define THREADS  256            // 4 waves x 16 tokens, each wave does all 64 experts
#define NCHUNK   64             // K chunks of 32
#define WCHUNK_B 12288          // W frag bytes per K32 chunk: 3 planes * 4 n * 64 lanes * 16
#define NBUF     4

typedef __attribute__((ext_vector_type(8))) short bf16x8;   // 8 bf16 = 4 VGPR
typedef __attribute__((ext_vector_type(4))) float f32x4;    // MFMA C/D

__device__ __forceinline__ uint bf16_rne(float x) {
    uint u = __float_as_uint(x);
    return (u + 0x7fffu + ((u >> 16) & 1u)) >> 16;
}
__device__ __forceinline__ float bf16f(uint h) { return __uint_as_float(h << 16); }

// direct global->LDS, 16 B per lane; LDS dest = wave-uniform base + lane*16
__device__ __forceinline__ void stage16(const void* g, void* l)
{
    typedef __attribute__((address_space(1))) const unsigned int gu32;
    typedef __attribute__((address_space(3))) unsigned int lu32;
    __builtin_amdgcn_global_load_lds((gu32*)g, (lu32*)l, 16, 0, 0);
}

// x[8] -> h/m/l bf16x8. h,m: RNE; l: trunc. Identical to R4-R7 -> same logits.
__device__ __forceinline__ void split3(float4 u, float4 v, bf16x8& H, bf16x8& M, bf16x8& L)
{
    const float x[8] = {u.x, u.y, u.z, u.w, v.x, v.y, v.z, v.w};
    uint hw[8], mw[8], lw[8];
#pragma unroll
    for (int j = 0; j < 8; ++j) {
        const uint ux = __float_as_uint(x[j]);
        hw[j] = (ux + 0x7fffu + ((ux >> 16) & 1u)) & 0xffff0000u;   // RNE, low16 zero
        const float r1 = x[j] - __uint_as_float(hw[j]);             // exact
        const uint ur = __float_as_uint(r1);
        mw[j] = (ur + 0x7fffu + ((ur >> 16) & 1u)) & 0xffff0000u;   // RNE
        lw[j] = __float_as_uint(r1 - __uint_as_float(mw[j]));       // trunc via pack
    }
    uint* hp = (uint*)&H; uint* mp = (uint*)&M; uint* lp = (uint*)&L;
#pragma unroll
    for (int w = 0; w < 4; ++w) {
        hp[w] = __builtin_amdgcn_perm(hw[2 * w + 1], hw[2 * w], 0x07060302u);
        mp[w] = __builtin_amdgcn_perm(mw[2 * w + 1], mw[2 * w], 0x07060302u);
        lp[w] = __builtin_amdgcn_perm(lw[2 * w + 1], lw[2 * w], 0x07060302u);
    }
}

// W[64][2048] fp32 -> fragment-major h/m/l planes, K32-block layout (same as R5-R7).
// Byte offs: c32*12288 + p*4096 + n*1024 + lane*16; e = n*16+row, k = c32*32+g*8+j,
// lane = g*16+row.
__global__ void w_prep(const float* __restrict__ W, ushort* __restrict__ WF)
{
    const int e = blockIdx.x;
    const int t = threadIdx.x;
    const float4 a = *(const float4*)(W + (size_t)e * EMBED_D + t * 8);
    const float4 b = *(const float4*)(W + (size_t)e * EMBED_D + t * 8 + 4);
    const float ev[8] = {a.x, a.y, a.z, a.w, b.x, b.y, b.z, b.w};
    ushort h[8], m[8], l[8];
#pragma unroll
    for (int j = 0; j < 8; ++j) {
        const uint hh = bf16_rne(ev[j]);
        const float r1 = ev[j] - bf16f(hh);
        const uint mm = bf16_rne(r1);
        const uint ll = bf16_rne(r1 - bf16f(mm));
        h[j] = (ushort)hh; m[j] = (ushort)mm; l[j] = (ushort)ll;
    }
    const int c = t >> 2;           // K32 block
    const int g = t & 3;
    const int lane = g * 16 + (e & 15);
    const int n    = e >> 4;
    const size_t base = (size_t)c * 6144 + (size_t)n * 512 + (size_t)lane * 8;  // ushorts
    ushort4* H = (ushort4*)(WF + base);
    ushort4* M = (ushort4*)(WF + base + 2048);
    ushort4* L = (ushort4*)(WF + base + 4096);
    H[0] = make_ushort4(h[0], h[1], h[2], h[3]); H[1] = make_ushort4(h[4], h[5], h[6], h[7]);
    M[0] = make_ushort4(m[0], m[1], m[2], m[3]); M[1] = make_ushort4(m[4], m[5], m[6], m[7]);
    L[0] = make_ushort4(l[0], l[1], l[2], l[3]); L[1] = make_ushort4(l[4], l[5], l[6], l[7]);
}

__global__ __launch_bounds__(THREADS, 2) void moe_gate_main(
    const float*  __restrict__ X,    // [n_tok][2048] fp32
    const ushort* __restrict__ WF,   // fragment-major W planes (768 KB)
    float* __restrict__ out,
    float* __restrict__ ws,
    int n_tok)
{
    // 4 W pipeline slots (48 KB); reused as Lp[64][65] after loop.
    __shared__ __align__(16) char smem[NBUF * WCHUNK_B];
    __shared__ float sInvZ[TOK_BLK];
    __shared__ float sCnt[N_EXP];
    __shared__ float sColp[4][N_EXP];

    const int tid  = threadIdx.x;
    const int lane = tid & 63;
    const int wv   = __builtin_amdgcn_readfirstlane(tid >> 6);  // 0..3 = 16-token group
    const int row  = lane & 15;
    const int g    = lane >> 4;
    const int t0   = blockIdx.x * TOK_BLK;

    // X straight to registers: lane holds token (wv*16+row), k-group g (8 floats/chunk)
    const float* xbase = X + (size_t)(t0 + wv * 16 + row) * EMBED_D + (g << 3);
    // W staging source: this wave's 3 x 1KB pieces per chunk (linear copy)
    const char* wsrc = (const char*)WF + (size_t)(wv * 1024) + lane * 16;

    f32x4 acc[4];
#pragma unroll
    for (int n = 0; n < 4; ++n) acc[n] = (f32x4){0.f, 0.f, 0.f, 0.f};

    float4 xr[4][2];   // X ring, statically indexed (4x unrolled loop)

#define STAGE_W(C, SLOT)                                                        \
    {                                                                           \
        const char* gw = wsrc + (size_t)(C) * WCHUNK_B;                         \
        char* db = smem + (SLOT) * WCHUNK_B;                                    \
        stage16(gw,        db + (0 * 4 + wv) * 1024);                           \
        stage16(gw + 4096, db + (1 * 4 + wv) * 1024);                           \
        stage16(gw + 8192, db + (2 * 4 + wv) * 1024);                           \
    }
#define LOAD_X(C, SLOT)                                                         \
    {                                                                           \
        const float* xs = xbase + (C) * 32;                                     \
        xr[SLOT][0] = *(const float4*)(xs);                                     \
        xr[SLOT][1] = *(const float4*)(xs + 4);                                 \
    }

    // ---- prologue, issue order: X0 W0 X1 W1 X2 W2 X3 ----
    LOAD_X(0, 0)
    STAGE_W(0, 0)
    __builtin_amdgcn_sched_barrier(0);
    LOAD_X(1, 1)
    STAGE_W(1, 1)
    __builtin_amdgcn_sched_barrier(0);
    LOAD_X(2, 2)
    STAGE_W(2, 2)
    __builtin_amdgcn_sched_barrier(0);
    LOAD_X(3, 3)
    __builtin_amdgcn_sched_barrier(0);

    // one chunk body. VM = vmcnt immediate; DO_W/DO_X = issue prefetches.
#define BODY(C, U, VM, DO_W, DO_X)                                              \
    {                                                                           \
        asm volatile("s_waitcnt vmcnt(" #VM ")" ::: "memory");                  \
        __builtin_amdgcn_sched_barrier(0);                                      \
        __builtin_amdgcn_s_barrier();                                           \
        __builtin_amdgcn_sched_barrier(0);                                      \
        if (DO_W) STAGE_W((C) + 3, ((U) + 3) & 3)                               \
        __builtin_amdgcn_sched_barrier(0);                                      \
        bf16x8 ah, am, al;                                                      \
        split3(xr[U][0], xr[U][1], ah, am, al);                                 \
        if (DO_X) LOAD_X((C) + 4, U)                                            \
        __builtin_amdgcn_sched_barrier(0);                                      \
        const char* bb = smem + (U) * WCHUNK_B;                                 \
        _Pragma("unroll")                                                       \
        for (int n = 0; n < 4; ++n) {                                           \
            const char* bp = bb + n * 1024 + (lane << 4);                       \
            const bf16x8 bh = *(const bf16x8*)(bp);                             \
            const bf16x8 bm = *(const bf16x8*)(bp + 4096);                      \
            const bf16x8 bl = *(const bf16x8*)(bp + 8192);                      \
            acc[n] = __builtin_amdgcn_mfma_f32_16x16x32_bf16(ah, bh, acc[n], 0, 0, 0); \
            acc[n] = __builtin_amdgcn_mfma_f32_16x16x32_bf16(am, bh, acc[n], 0, 0, 0); \
            acc[n] = __builtin_amdgcn_mfma_f32_16x16x32_bf16(ah, bm, acc[n], 0, 0, 0); \
            acc[n] = __builtin_amdgcn_mfma_f32_16x16x32_bf16(al, bh, acc[n], 0, 0, 0); \
            acc[n] = __builtin_amdgcn_mfma_f32_16x16x32_bf16(ah, bl, acc[n], 0, 0, 0); \
            acc[n] = __builtin_amdgcn_mfma_f32_16x16x32_bf16(am, bm, acc[n], 0, 0, 0); \
        }                                                                       \
        __builtin_amdgcn_sched_barrier(0);                                      \
    }

    // main: c = 0..59 (15 macro-iters), full issue, steady vmcnt(12)
    for (int cc = 0; cc < NCHUNK - 4; cc += 4) {
        BODY(cc + 0, 0, 12, 1, 1)
        BODY(cc + 1, 1, 12, 1, 1)
        BODY(cc + 2, 2, 12, 1, 1)
        BODY(cc + 3, 3, 12, 1, 1)
    }
    // tail: c = 60..63
    BODY(60, 0, 12, 1, 0)   // issues W(63); no X
    BODY(61, 1, 10, 0, 0)
    BODY(62, 2, 5, 0, 0)
    BODY(63, 3, 0, 0, 0)
#undef BODY
#undef STAGE_W
#undef LOAD_X

    __syncthreads();   // all waves done -> W slots reusable as Lp

    // reuse smem as logits [tok][exp], stride 65 (16640 B <= 49152 B)
    float (*Lp)[N_EXP + 1] = (float (*)[N_EXP + 1])smem;
    // C/D layout: token = wv*16 + g*4 + reg, expert = n*16 + (lane&15)
#pragma unroll
    for (int n = 0; n < 4; ++n)
#pragma unroll
        for (int r = 0; r < 4; ++r)
            Lp[wv * 16 + g * 4 + r][n * 16 + row] = acc[n][r];
    if (tid < N_EXP) sCnt[tid] = 0.f;
    __syncthreads();

    // per-token softmax + top-8 (threads 0..63)
    if (tid < TOK_BLK) {
        const int t = tid;
        float mx = -1e30f;
        for (int e = 0; e < N_EXP; ++e)
            mx = fmaxf(mx, Lp[t][e]);
        float Z = 0.f;
        float tv[K_TOP]; int ti[K_TOP];
#pragma unroll
        for (int j = 0; j < K_TOP; ++j) { tv[j] = -1e30f; ti[j] = 0; }
        for (int e = 0; e < N_EXP; ++e) {
            const float s = __expf(Lp[t][e] - mx);
            Lp[t][e] = s;                 // unnormalized score for Pi pass
            Z += s;
            float v = s; int id = e;
#pragma unroll
            for (int j = 0; j < K_TOP; ++j) {  // strict > : ties keep lower idx
                if (v > tv[j]) {
                    float fv = tv[j]; tv[j] = v; v = fv;
                    int   fi = ti[j]; ti[j] = id; id = fi;
                }
            }
        }
        const float invZ = 1.0f / Z;
        sInvZ[t] = invZ;
        const size_t ob = (size_t)(t0 + t) * K_TOP;
        const size_t wo = (size_t)n_tok * K_TOP;
#pragma unroll
        for (int j = 0; j < K_TOP; ++j) {
            out[ob + j]      = (float)ti[j];
            out[wo + ob + j] = tv[j] * invZ;
            atomicAdd(&sCnt[ti[j]], 1.0f);
        }
    }
    __syncthreads();

    // per-expert score sums (Pi numerator): 4 groups x 16 tokens
    {
        const int e = tid & 63, g2 = tid >> 6;
        float s = 0.f;
#pragma unroll
        for (int i = 0; i < 16; ++i) {
            const int t = g2 * 16 + i;
            s += Lp[t][e] * sInvZ[t];
        }
        sColp[g2][e] = s;
    }
    __syncthreads();
    if (tid < N_EXP) {
        float s = 0.f;
#pragma unroll
        for (int g2 = 0; g2 < 4; ++g2) s += sColp[g2][tid];
        atomicAdd(&ws[64 + tid], s);
        atomicAdd(&ws[tid], sCnt[tid]);
    }
}

__global__ void moe_aux(const float* __restrict__ ws, float* __restrict__ out, int n_tok)
{
    const int e = threadIdx.x;   // 64 threads
    const float counts = ws[e];
    const float ssum   = ws[64 + e];
    const float Pi = ssum / (float)n_tok;
    const float ce = counts / ((float)n_tok * (float)K_TOP);
    float term = Pi * ce * (float)N_EXP;
    for (int off = 32; off; off >>= 1) term += __shfl_down(term, off);
    if (e == 0) out[(size_t)2 * n_tok * K_TOP] = term * 0.01f;
}

extern "C" void kernel_launch(void* const* d_in, const int* in_sizes, int n_in,
                              void* d_out, int out_size, void* d_ws, size_t ws_size,
                              hipStream_t stream)
{
    const float* X = (const float*)d_in[0];
    const float* W = (const float*)d_in[1];
    float* out = (float*)d_out;
    float* ws  = (float*)d_ws;
    const int n_tok = in_sizes[0] / EMBED_D;   // 32768

    // workspace: [0..255] floats counters | fragment-major W planes (768 KB)
    ushort* WF = (ushort*)(ws + 256);

    hipMemsetAsync(ws, 0, 2 * N_EXP * sizeof(float), stream);
    w_prep<<<N_EXP, 256, 0, stream>>>(W, WF);
    moe_gate_main<<<n_tok / TOK_BLK, THREADS, 0, stream>>>(X, WF, out, ws, n_tok);
    moe_aux<<<1, 64, 0, stream>>>(ws, out, n_tok);
}